// Round 1
// 15495.595 us; speedup vs baseline: 2.6328x; 2.6328x over previous
//
#include <hip/hip_runtime.h>
#include <math.h>

// ---------------------------------------------------------------------------
// KashfModel forward on MI355X. Round 1: all GEMMs -> MFMA bf16 hi/lo split
// (fp32-level accuracy, 3 MFMA per product). Weights pre-transposed/split once
// per launch into workspace (col-major bf16 planes, K padded to x32).
// Fallback to fp32 SMEM GEMM if workspace is too small (~420 MB needed).
// B=2 T=1024 D=1024 E=512 H=16 HD=64 EXP=1024 DFF=1365 L=6 V=50257
// ---------------------------------------------------------------------------

namespace {

constexpr int kB = 2, kT = 1024, kV = 50257, kD = 1024, kE = 512;
constexpr int kH = 16, kHD = 64, kEXP = 1024, kDFF = 1365, kL = 6;
constexpr int kN = kB * kT; // 2048 tokens
constexpr float kCAP = 50.0f;
constexpr float kEPS = 1e-6f;

typedef __attribute__((ext_vector_type(8))) short bf16x8;
typedef __attribute__((ext_vector_type(4))) float f32x4;

// ---- bf16 helpers (RNE) ----------------------------------------------------
__device__ inline unsigned short f2bf(float f) {
  unsigned int x = __float_as_uint(f);
  unsigned int r = x + 0x7fffu + ((x >> 16) & 1u);
  return (unsigned short)(r >> 16);
}
__device__ inline float bf2f(unsigned short u) {
  return __uint_as_float(((unsigned int)u) << 16);
}

// ---------------- rope tables: cos/sin[t][i], i<32, theta=500000 ------------
__global__ __launch_bounds__(256) void rope_tables_k(float* __restrict__ cost,
                                                     float* __restrict__ sint) {
  int idx = blockIdx.x * 256 + threadIdx.x; // kT*32 = 32768
  int t = idx >> 5, i = idx & 31;
  float inv = __powf(500000.0f, -(float)i / 32.0f);
  float ang = (float)t * inv;
  cost[idx] = cosf(ang);
  sint[idx] = sinf(ang);
}

// ---------------- OLD fp32 GEMM (fallback path only) ------------------------
template <bool ACCUM, bool EMBED>
__global__ __launch_bounds__(256) void gemm128_k(const float* __restrict__ A,
                                                 const float* __restrict__ Bm,
                                                 float* __restrict__ C, int K, int M,
                                                 const int* __restrict__ tok) {
  __shared__ float As[8][132];
  __shared__ float Bs[8][132];
  const int tid = threadIdx.x;
  const int tx = tid & 15, ty = tid >> 4;
  const int rowBase = blockIdx.y * 128;
  const int colBase = blockIdx.x * 128;
  float acc[8][8];
#pragma unroll
  for (int i = 0; i < 8; i++)
#pragma unroll
    for (int j = 0; j < 8; j++) acc[i][j] = 0.0f;

  for (int k0 = 0; k0 < K; k0 += 8) {
#pragma unroll
    for (int i = 0; i < 4; i++) {
      int lin = tid + i * 256;
      int r = lin >> 3, kk = lin & 7;
      int gk = k0 + kk;
      float v = 0.0f;
      if (gk < K) {
        int row = rowBase + r;
        size_t arow = EMBED ? (size_t)tok[row] : (size_t)row;
        v = A[arow * K + gk];
      }
      As[kk][r] = v;
    }
#pragma unroll
    for (int i = 0; i < 4; i++) {
      int lin = tid + i * 256;
      int kk = lin >> 7, c = lin & 127;
      int gk = k0 + kk, gc = colBase + c;
      Bs[kk][c] = (gk < K && gc < M) ? Bm[(size_t)gk * M + gc] : 0.0f;
    }
    __syncthreads();
#pragma unroll
    for (int kk = 0; kk < 8; kk++) {
      float av[8], bv[8];
#pragma unroll
      for (int i = 0; i < 8; i++) av[i] = As[kk][ty * 8 + i];
#pragma unroll
      for (int j = 0; j < 8; j++) bv[j] = Bs[kk][tx * 8 + j];
#pragma unroll
      for (int i = 0; i < 8; i++)
#pragma unroll
        for (int j = 0; j < 8; j++) acc[i][j] += av[i] * bv[j];
    }
    __syncthreads();
  }
#pragma unroll
  for (int i = 0; i < 8; i++) {
    int r = rowBase + ty * 8 + i;
#pragma unroll
    for (int j = 0; j < 8; j++) {
      int c = colBase + tx * 8 + j;
      if (c < M) {
        size_t idx = (size_t)r * M + c;
        if (ACCUM)
          C[idx] += acc[i][j];
        else
          C[idx] = acc[i][j];
      }
    }
  }
}

// ---------------- weight transpose+split: W[K][M] f32 -> Wt[M][Kp] bf16 x2 --
__global__ __launch_bounds__(256) void wconv_k(const float* __restrict__ W,
                                               unsigned short* __restrict__ Wh,
                                               unsigned short* __restrict__ Wl,
                                               int K, int M, int Kp) {
  __shared__ float tile[32][33];
  const int kb = blockIdx.y * 32, mb = blockIdx.x * 32;
#pragma unroll
  for (int i = 0; i < 4; i++) {
    int kk = (threadIdx.x >> 5) + i * 8; // k within tile
    int mm = threadIdx.x & 31;           // m within tile (coalesced)
    int gk = kb + kk, gm = mb + mm;
    tile[kk][mm] = (gk < K && gm < M) ? W[(size_t)gk * M + gm] : 0.0f;
  }
  __syncthreads();
#pragma unroll
  for (int i = 0; i < 4; i++) {
    int mm = (threadIdx.x >> 5) + i * 8; // m within tile
    int kk = threadIdx.x & 31;           // k within tile (coalesced store)
    int gm = mb + mm, gk = kb + kk;
    if (gm < M) {
      float v = tile[kk][mm];
      unsigned short h = f2bf(v);
      size_t idx = (size_t)gm * Kp + gk;
      Wh[idx] = h;
      Wl[idx] = f2bf(v - bf2f(h));
    }
  }
}

// ---------------- activation split: X[N][K] f32 -> Ah/Al[N][Kp] bf16 --------
// tok != nullptr: row source is gathered (embedding table).
__global__ __launch_bounds__(256) void aconv_k(const float* __restrict__ X,
                                               unsigned short* __restrict__ Ah,
                                               unsigned short* __restrict__ Al,
                                               int K, int Kp,
                                               const int* __restrict__ tok) {
  int n = blockIdx.x;
  size_t src = tok ? (size_t)tok[n] : (size_t)n;
  const float* row = X + src * K;
  unsigned short* ah = Ah + (size_t)n * Kp;
  unsigned short* al = Al + (size_t)n * Kp;
  for (int k = threadIdx.x; k < Kp; k += 256) {
    float v = (k < K) ? row[k] : 0.0f;
    unsigned short h = f2bf(v);
    ah[k] = h;
    al[k] = f2bf(v - bf2f(h));
  }
}

// ---------------- MFMA GEMM, hi/lo split ------------------------------------
// C[2048 x M] = (Ah+Al)[2048 x Kp] @ (Bh+Bl)^T where B planes are [M][Kp].
// 128x128 tile, BK=32, 4 waves each 64x64 (4x4 frags of 16x16x32 bf16).
// acc += ah*bh + ah*bl + al*bh   (al*bl dropped: ~2^-18 relative)
template <bool ACCUM>
__global__ __launch_bounds__(256, 2) void gemm_bf16s_k(
    const unsigned short* __restrict__ Ah, const unsigned short* __restrict__ Al,
    const unsigned short* __restrict__ Bh, const unsigned short* __restrict__ Bl,
    float* __restrict__ C, int Kp, int M) {
  __shared__ unsigned short As[2][128][40]; // [plane][row][k], pad 40 (80B rows)
  __shared__ unsigned short Bs[2][128][40]; // [plane][col][k]
  const int tid = threadIdx.x;
  const int wave = tid >> 6, lane = tid & 63;
  const int l15 = lane & 15, l4 = lane >> 4;
  const int wr = (wave >> 1) * 64, wc = (wave & 1) * 64;
  const int rowBase = blockIdx.y * 128, colBase = blockIdx.x * 128;

  f32x4 acc[4][4];
#pragma unroll
  for (int m = 0; m < 4; m++)
#pragma unroll
    for (int n = 0; n < 4; n++)
#pragma unroll
      for (int r = 0; r < 4; r++) acc[m][n][r] = 0.0f;

  for (int k0 = 0; k0 < Kp; k0 += 32) {
    // stage: 16B chunks; i=0,1 -> hi plane rows 0-63/64-127; i=2,3 -> lo plane
#pragma unroll
    for (int i = 0; i < 4; i++) {
      int flin = tid + (i & 1) * 256; // 0..511
      int r = flin >> 2;              // 0..127
      int kc = (flin & 3) * 8;        // short offset within 32
      int pl = i >> 1;
      const unsigned short* sa =
          (pl ? Al : Ah) + (size_t)(rowBase + r) * Kp + k0 + kc;
      *(int4*)&As[pl][r][kc] = *(const int4*)sa;
      int4 bv = {0, 0, 0, 0};
      int col = colBase + r;
      if (col < M)
        bv = *(const int4*)((pl ? Bl : Bh) + (size_t)col * Kp + k0 + kc);
      *(int4*)&Bs[pl][r][kc] = bv;
    }
    __syncthreads();

    bf16x8 ah[4], al[4], bh[4], bl[4];
#pragma unroll
    for (int m = 0; m < 4; m++) {
      ah[m] = *reinterpret_cast<const bf16x8*>(&As[0][wr + m * 16 + l15][l4 * 8]);
      al[m] = *reinterpret_cast<const bf16x8*>(&As[1][wr + m * 16 + l15][l4 * 8]);
    }
#pragma unroll
    for (int n = 0; n < 4; n++) {
      bh[n] = *reinterpret_cast<const bf16x8*>(&Bs[0][wc + n * 16 + l15][l4 * 8]);
      bl[n] = *reinterpret_cast<const bf16x8*>(&Bs[1][wc + n * 16 + l15][l4 * 8]);
    }
#pragma unroll
    for (int m = 0; m < 4; m++)
#pragma unroll
      for (int n = 0; n < 4; n++) {
        acc[m][n] = __builtin_amdgcn_mfma_f32_16x16x32_bf16(ah[m], bh[n], acc[m][n], 0, 0, 0);
        acc[m][n] = __builtin_amdgcn_mfma_f32_16x16x32_bf16(ah[m], bl[n], acc[m][n], 0, 0, 0);
        acc[m][n] = __builtin_amdgcn_mfma_f32_16x16x32_bf16(al[m], bh[n], acc[m][n], 0, 0, 0);
      }
    __syncthreads();
  }

  // epilogue: D layout col=lane&15, row=(lane>>4)*4+reg
  const int row0 = rowBase + wr + l4 * 4;
#pragma unroll
  for (int m = 0; m < 4; m++) {
#pragma unroll
    for (int n = 0; n < 4; n++) {
      int col = colBase + wc + n * 16 + l15;
      if (col < M) {
#pragma unroll
        for (int r = 0; r < 4; r++) {
          size_t idx = (size_t)(row0 + m * 16 + r) * M + col;
          if (ACCUM)
            C[idx] += acc[m][n][r];
          else
            C[idx] = acc[m][n][r];
        }
      }
    }
  }
}

// ---------------- RMS norm over D=1024: one block per row -------------------
__global__ __launch_bounds__(256) void rms_k(const float* __restrict__ x,
                                             const float* __restrict__ w,
                                             float* __restrict__ out) {
  int n = blockIdx.x;
  const float* row = x + (size_t)n * kD;
  float v[4];
  float ss = 0.0f;
#pragma unroll
  for (int i = 0; i < 4; i++) {
    v[i] = row[threadIdx.x + i * 256];
    ss += v[i] * v[i];
  }
#pragma unroll
  for (int off = 32; off > 0; off >>= 1) ss += __shfl_down(ss, off);
  __shared__ float red[4];
  if ((threadIdx.x & 63) == 0) red[threadIdx.x >> 6] = ss;
  __syncthreads();
  float tot = red[0] + red[1] + red[2] + red[3];
  float scale = rsqrtf(tot * (1.0f / kD) + kEPS);
  float* orow = out + (size_t)n * kD;
#pragma unroll
  for (int i = 0; i < 4; i++) {
    int d = threadIdx.x + i * 256;
    orow[d] = v[i] * scale * w[d];
  }
}

// ---------------- per-head RMS (over 64) + RoPE, in place -------------------
__global__ __launch_bounds__(256) void qk_norm_rope_k(float* __restrict__ qk,
                                                      const float* __restrict__ nw,
                                                      const float* __restrict__ cost,
                                                      const float* __restrict__ sint,
                                                      int nh) {
  int row = blockIdx.x * 16 + (threadIdx.x >> 4);
  int lane = threadIdx.x & 15;
  float* r = qk + (size_t)row * 64;
  float v[4];
  float ss = 0.0f;
#pragma unroll
  for (int i = 0; i < 4; i++) {
    v[i] = r[lane * 4 + i];
    ss += v[i] * v[i];
  }
#pragma unroll
  for (int m = 1; m < 16; m <<= 1) ss += __shfl_xor(ss, m);
  float scale = rsqrtf(ss * (1.0f / 64.0f) + kEPS);
  float nv[4];
#pragma unroll
  for (int i = 0; i < 4; i++) nv[i] = v[i] * scale * nw[lane * 4 + i];
  int tpos = (row / nh) & (kT - 1);
  float c0 = cost[tpos * 32 + lane * 2 + 0], s0 = sint[tpos * 32 + lane * 2 + 0];
  float c1 = cost[tpos * 32 + lane * 2 + 1], s1 = sint[tpos * 32 + lane * 2 + 1];
  r[lane * 4 + 0] = nv[0] * c0 - nv[1] * s0;
  r[lane * 4 + 1] = nv[0] * s0 + nv[1] * c0;
  r[lane * 4 + 2] = nv[2] * c1 - nv[3] * s1;
  r[lane * 4 + 3] = nv[2] * s1 + nv[3] * c1;
}

// ---------------- flash attention (causal, tanh-capped, MQA) ----------------
__global__ __launch_bounds__(64) void attn_flash_k(const float* __restrict__ q,
                                                   const float* __restrict__ k,
                                                   const float* __restrict__ v,
                                                   float* __restrict__ out) {
  const int b = blockIdx.z, h = blockIdx.y, qb = blockIdx.x;
  const int tid = threadIdx.x;
  const int t = qb * 64 + tid;
  const float* qrow = q + (((size_t)(b * kT + t)) * kH + h) * kHD;
  float qreg[64];
#pragma unroll
  for (int d = 0; d < 64; d++) qreg[d] = qrow[d] * 0.125f;
  float O[64];
#pragma unroll
  for (int d = 0; d < 64; d++) O[d] = 0.0f;
  float m = -INFINITY, l = 0.0f;
  __shared__ float ks[32][64];
  __shared__ float vs[32][64];
  const int smax = qb * 64 + 63;
  for (int s0 = 0; s0 <= smax; s0 += 32) {
#pragma unroll 4
    for (int r = 0; r < 32; r++) {
      ks[r][tid] = k[((size_t)(b * kT + s0 + r)) * 64 + tid];
      vs[r][tid] = v[((size_t)(b * kT + s0 + r)) * 64 + tid];
    }
    __syncthreads();
    int jend = t - s0 + 1;
    if (jend > 32) jend = 32;
    for (int j = 0; j < jend; j++) {
      float dot = 0.0f;
#pragma unroll
      for (int d = 0; d < 64; d++) dot += qreg[d] * ks[j][d];
      float sc = kCAP * tanhf(dot * (1.0f / kCAP));
      float mn = fmaxf(m, sc);
      float corr = __expf(m - mn);
      float p = __expf(sc - mn);
      l = l * corr + p;
#pragma unroll
      for (int d = 0; d < 64; d++) O[d] = O[d] * corr + p * vs[j][d];
      m = mn;
    }
    __syncthreads();
  }
  float invl = 1.0f / l;
  float* orow = out + ((size_t)(b * kT + t)) * (kH * kHD) + h * kHD;
#pragma unroll
  for (int d = 0; d < 64; d++) orow[d] = O[d] * invl;
}

// ---------------- router: wave per token, fp32 dot, argmax ------------------
__global__ __launch_bounds__(256) void router_k(const float* __restrict__ xn,
                                                const float* __restrict__ rw,
                                                const float* __restrict__ rb,
                                                int* __restrict__ eidx) {
  int n = blockIdx.x * 4 + (threadIdx.x >> 6);
  int lane = threadIdx.x & 63;
  const float* row = xn + (size_t)n * kD;
  float l0 = 0.0f, l1 = 0.0f;
  for (int kk = lane; kk < kD; kk += 64) {
    float xv = row[kk];
    l0 += xv * rw[kk * 2 + 0];
    l1 += xv * rw[kk * 2 + 1];
  }
#pragma unroll
  for (int off = 32; off > 0; off >>= 1) {
    l0 += __shfl_down(l0, off);
    l1 += __shfl_down(l1, off);
  }
  if (lane == 0) eidx[n] = (l1 + rb[1] > l0 + rb[0]) ? 1 : 0;
}

// ---------------- elementwise helpers ---------------------------------------
__global__ __launch_bounds__(256) void silu_mul_k(const float* __restrict__ g,
                                                  const float* __restrict__ u,
                                                  float* __restrict__ out, int n) {
  int i = blockIdx.x * 256 + threadIdx.x;
  if (i < n) {
    float gv = g[i];
    float s = gv / (1.0f + __expf(-gv));
    out[i] = s * u[i];
  }
}

__global__ __launch_bounds__(256) void add_loop_emb_k(const float* __restrict__ h,
                                                      float* __restrict__ x, int t) {
  int idx = blockIdx.x * 256 + threadIdx.x;
  int d = idx & (kD - 1);
  float add = 0.0f;
  if (d < 256) {
    float f = __powf(10000.0f, -(float)d / 256.0f);
    add = sinf((float)t * f);
  } else if (d < 512) {
    float f = __powf(10000.0f, -(float)(d - 256) / 256.0f);
    add = cosf((float)t * f);
  }
  x[idx] = h[idx] + add;
}

__global__ __launch_bounds__(256) void moe_combine_k(float* __restrict__ x,
                                                     const float* __restrict__ y0,
                                                     const float* __restrict__ y1,
                                                     const float* __restrict__ ys,
                                                     const int* __restrict__ eidx) {
  int idx = blockIdx.x * 256 + threadIdx.x;
  int n = idx >> 10;
  const float* y = eidx[n] ? y1 : y0;
  x[idx] += y[idx] + ys[idx];
}

__global__ __launch_bounds__(256) void h_update_k(float* __restrict__ h,
                                                  const float* __restrict__ e,
                                                  const float* __restrict__ x,
                                                  const float* __restrict__ logA,
                                                  const float* __restrict__ logdt,
                                                  const float* __restrict__ Bv,
                                                  const float* __restrict__ gate, int t) {
  int idx = blockIdx.x * 256 + threadIdx.x;
  int d = idx & (kD - 1);
  float z = logdt[0] + logA[d];
  z = fminf(fmaxf(z, -20.0f), 20.0f);
  float A = __expf(-__expf(z));
  float gv = gate[t];
  float g = 1.0f / (1.0f + __expf(-gv));
  h[idx] = A * h[idx] + Bv[d] * e[idx] + g * x[idx];
}

} // namespace

// ---------------------------------------------------------------------------
extern "C" void kernel_launch(void* const* d_in, const int* in_sizes, int n_in,
                              void* d_out, int out_size, void* d_ws, size_t ws_size,
                              hipStream_t stream) {
  const int* tok = (const int*)d_in[0];
  const float* embed_table = (const float*)d_in[1];
  const float* embed_proj = (const float*)d_in[2];
  const float* pre_an = (const float*)d_in[3];
  const float* pre_fn = (const float*)d_in[4];
  const float* pre_wq = (const float*)d_in[5];
  const float* pre_wk = (const float*)d_in[6];
  const float* pre_wv = (const float*)d_in[7];
  const float* pre_wo = (const float*)d_in[8];
  const float* pre_qn = (const float*)d_in[9];
  const float* pre_kn = (const float*)d_in[10];
  const float* pre_g = (const float*)d_in[11];
  const float* pre_u = (const float*)d_in[12];
  const float* pre_d = (const float*)d_in[13];
  const float* rec_an = (const float*)d_in[14];
  const float* rec_fn = (const float*)d_in[15];
  const float* rec_wq = (const float*)d_in[16];
  const float* rec_wk = (const float*)d_in[17];
  const float* rec_wv = (const float*)d_in[18];
  const float* rec_wo = (const float*)d_in[19];
  const float* rec_qn = (const float*)d_in[20];
  const float* rec_kn = (const float*)d_in[21];
  const float* rec_router = (const float*)d_in[22];
  const float* rec_rbias = (const float*)d_in[23];
  const float* rec_eg = (const float*)d_in[24];
  const float* rec_eu = (const float*)d_in[25];
  const float* rec_ed = (const float*)d_in[26];
  const float* rec_sg = (const float*)d_in[27];
  const float* rec_su = (const float*)d_in[28];
  const float* rec_sd = (const float*)d_in[29];
  const float* lti_logA = (const float*)d_in[30];
  const float* lti_logdt = (const float*)d_in[31];
  const float* lti_B = (const float*)d_in[32];
  const float* gate_emb = (const float*)d_in[33];
  const float* coda_an = (const float*)d_in[34];
  const float* coda_fn = (const float*)d_in[35];
  const float* coda_wq = (const float*)d_in[36];
  const float* coda_wk = (const float*)d_in[37];
  const float* coda_wv = (const float*)d_in[38];
  const float* coda_wo = (const float*)d_in[39];
  const float* coda_qn = (const float*)d_in[40];
  const float* coda_kn = (const float*)d_in[41];
  const float* coda_g = (const float*)d_in[42];
  const float* coda_u = (const float*)d_in[43];
  const float* coda_d = (const float*)d_in[44];
  const float* final_norm = (const float*)d_in[45];
  const float* lm_head = (const float*)d_in[46];
  float* out = (float*)d_out;

  // ---- workspace bump allocator ----
  char* base = (char*)d_ws;
  size_t off = 0;
  auto alloc = [&](size_t bytes) -> void* {
    void* p = base + off;
    off += (bytes + 255) & ~(size_t)255;
    return p;
  };

  const size_t ND = (size_t)kN * kD;      // 2097152
  const size_t NDFF = (size_t)kN * kDFF;  // 2795520
  float* e_buf = (float*)alloc(ND * 4);
  float* h_buf = (float*)alloc(ND * 4);
  float* x_buf = (float*)alloc(ND * 4);
  float* xn_buf = (float*)alloc(ND * 4);
  float* q_buf = (float*)alloc(ND * 4);   // reused as ybuf0
  float* a_buf = (float*)alloc(ND * 4);   // reused as ybuf1
  float* ys_buf = (float*)alloc(ND * 4);
  float* g_buf = (float*)alloc(NDFF * 4);
  float* u_buf = (float*)alloc(NDFF * 4);
  float* k_buf = (float*)alloc((size_t)kN * 64 * 4);
  float* v_buf = (float*)alloc((size_t)kN * 64 * 4);
  float* cost = (float*)alloc((size_t)kT * 32 * 4);
  float* sint = (float*)alloc((size_t)kT * 32 * 4);
  int* eidx = (int*)alloc((size_t)kN * 4);
  // activation bf16 planes (max Kp = 1376)
  const int maxKp = 1376;
  unsigned short* Ah = (unsigned short*)alloc((size_t)kN * maxKp * 2);
  unsigned short* Al = (unsigned short*)alloc((size_t)kN * maxKp * 2);

  // ---- weight cache registry ----
  struct WC {
    const float* W;
    int K, M, Kp;
    unsigned short *h, *l;
  };
  WC wcs[32];
  int nwc = 0;
  auto reg = [&](const float* W, int K, int M) -> int {
    int Kp = (K + 31) & ~31;
    WC w;
    w.W = W; w.K = K; w.M = M; w.Kp = Kp;
    w.h = (unsigned short*)alloc((size_t)M * Kp * 2);
    w.l = (unsigned short*)alloc((size_t)M * Kp * 2);
    wcs[nwc] = w;
    return nwc++;
  };

  const int iw_eproj = reg(embed_proj, kE, kD);
  const int iw_pre_wq = reg(pre_wq, kD, kH * kHD);
  const int iw_pre_wk = reg(pre_wk, kD, kHD);
  const int iw_pre_wv = reg(pre_wv, kD, kHD);
  const int iw_pre_wo = reg(pre_wo, kH * kHD, kD);
  const int iw_pre_g = reg(pre_g, kD, kDFF);
  const int iw_pre_u = reg(pre_u, kD, kDFF);
  const int iw_pre_d = reg(pre_d, kDFF, kD);
  const int iw_rec_wq = reg(rec_wq, kD, kH * kHD);
  const int iw_rec_wk = reg(rec_wk, kD, kHD);
  const int iw_rec_wv = reg(rec_wv, kD, kHD);
  const int iw_rec_wo = reg(rec_wo, kH * kHD, kD);
  const int iw_eg0 = reg(rec_eg, kD, kEXP);
  const int iw_eg1 = reg(rec_eg + (size_t)kD * kEXP, kD, kEXP);
  const int iw_eu0 = reg(rec_eu, kD, kEXP);
  const int iw_eu1 = reg(rec_eu + (size_t)kD * kEXP, kD, kEXP);
  const int iw_ed0 = reg(rec_ed, kEXP, kD);
  const int iw_ed1 = reg(rec_ed + (size_t)kEXP * kD, kEXP, kD);
  const int iw_sg = reg(rec_sg, kD, kEXP);
  const int iw_su = reg(rec_su, kD, kEXP);
  const int iw_sd = reg(rec_sd, kEXP, kD);
  const int iw_coda_wq = reg(coda_wq, kD, kH * kHD);
  const int iw_coda_wk = reg(coda_wk, kD, kHD);
  const int iw_coda_wv = reg(coda_wv, kD, kHD);
  const int iw_coda_wo = reg(coda_wo, kH * kHD, kD);
  const int iw_coda_g = reg(coda_g, kD, kDFF);
  const int iw_coda_u = reg(coda_u, kD, kDFF);
  const int iw_coda_d = reg(coda_d, kDFF, kD);
  const int iw_lm = reg(lm_head, kD, kV);

  const bool use_mfma = (off <= ws_size); // ~420 MB needed; fallback otherwise

  const dim3 blk256(256);
  const int ew_blocks = (int)(ND / 256);

  // ---- unified GEMM dispatch -------------------------------------------------
  // conv=true: (re)split A into Ah/Al first (mfma path only).
  auto do_gemm = [&](const float* Asrc, int wi, float* C, bool accum,
                     const int* tokp, bool conv) {
    const WC& w = wcs[wi];
    dim3 g((w.M + 127) / 128, kN / 128);
    if (use_mfma) {
      if (conv) aconv_k<<<kN, blk256, 0, stream>>>(Asrc, Ah, Al, w.K, w.Kp, tokp);
      if (accum)
        gemm_bf16s_k<true><<<g, blk256, 0, stream>>>(Ah, Al, w.h, w.l, C, w.Kp, w.M);
      else
        gemm_bf16s_k<false><<<g, blk256, 0, stream>>>(Ah, Al, w.h, w.l, C, w.Kp, w.M);
    } else {
      if (tokp)
        gemm128_k<false, true><<<g, blk256, 0, stream>>>(Asrc, w.W, C, w.K, w.M, tokp);
      else if (accum)
        gemm128_k<true, false><<<g, blk256, 0, stream>>>(Asrc, w.W, C, w.K, w.M, nullptr);
      else
        gemm128_k<false, false><<<g, blk256, 0, stream>>>(Asrc, w.W, C, w.K, w.M, nullptr);
    }
  };

  // ---- tables + weight conversion -------------------------------------------
  rope_tables_k<<<kT * 32 / 256, blk256, 0, stream>>>(cost, sint);
  if (use_mfma) {
    for (int i = 0; i < nwc; i++) {
      const WC& w = wcs[i];
      dim3 g((w.M + 31) / 32, w.Kp / 32);
      wconv_k<<<g, blk256, 0, stream>>>(w.W, w.h, w.l, w.K, w.M, w.Kp);
    }
  }

  // ---- embedding ----
  do_gemm(embed_table, iw_eproj, e_buf, false, tok, true);
  hipMemcpyAsync(h_buf, e_buf, ND * sizeof(float), hipMemcpyDeviceToDevice, stream);

  auto attn_block = [&](int iwq, int iwk, int iwv, int iwo, const float* an,
                        const float* qn, const float* kn, float* target) {
    rms_k<<<kN, blk256, 0, stream>>>(target, an, xn_buf);
    do_gemm(xn_buf, iwq, q_buf, false, nullptr, true);
    do_gemm(xn_buf, iwk, k_buf, false, nullptr, false);
    do_gemm(xn_buf, iwv, v_buf, false, nullptr, false);
    qk_norm_rope_k<<<kN * kH / 16, blk256, 0, stream>>>(q_buf, qn, cost, sint, kH);
    qk_norm_rope_k<<<kN / 16, blk256, 0, stream>>>(k_buf, kn, cost, sint, 1);
    attn_flash_k<<<dim3(kT / 64, kH, kB), dim3(64), 0, stream>>>(q_buf, k_buf, v_buf, a_buf);
    do_gemm(a_buf, iwo, target, true, nullptr, true);
  };

  auto swiglu_block = [&](int iwg, int iwu, int iwd, const float* fn, float* target) {
    rms_k<<<kN, blk256, 0, stream>>>(target, fn, xn_buf);
    do_gemm(xn_buf, iwg, g_buf, false, nullptr, true);
    do_gemm(xn_buf, iwu, u_buf, false, nullptr, false);
    silu_mul_k<<<(int)((NDFF + 255) / 256), blk256, 0, stream>>>(g_buf, u_buf, g_buf, (int)NDFF);
    do_gemm(g_buf, iwd, target, true, nullptr, true);
  };

  // ---- pre block ----
  attn_block(iw_pre_wq, iw_pre_wk, iw_pre_wv, iw_pre_wo, pre_an, pre_qn, pre_kn, h_buf);
  swiglu_block(iw_pre_g, iw_pre_u, iw_pre_d, pre_fn, h_buf);

  // ---- recurrent loop ----
  const int iw_eg[2] = {iw_eg0, iw_eg1};
  const int iw_eu[2] = {iw_eu0, iw_eu1};
  const int iw_ed[2] = {iw_ed0, iw_ed1};
  for (int t = 0; t < kL; t++) {
    add_loop_emb_k<<<ew_blocks, blk256, 0, stream>>>(h_buf, x_buf, t);
    attn_block(iw_rec_wq, iw_rec_wk, iw_rec_wv, iw_rec_wo, rec_an, rec_qn, rec_kn, x_buf);

    // MoE
    rms_k<<<kN, blk256, 0, stream>>>(x_buf, rec_fn, xn_buf);
    router_k<<<kN / 4, blk256, 0, stream>>>(xn_buf, rec_router, rec_rbias, eidx);
    float* ybuf[2] = {q_buf, a_buf}; // q/a free during MoE phase
    for (int ex = 0; ex < 2; ex++) {
      do_gemm(xn_buf, iw_eg[ex], g_buf, false, nullptr, true);
      do_gemm(xn_buf, iw_eu[ex], u_buf, false, nullptr, false);
      silu_mul_k<<<ew_blocks, blk256, 0, stream>>>(g_buf, u_buf, g_buf, (int)ND);
      do_gemm(g_buf, iw_ed[ex], ybuf[ex], false, nullptr, true);
    }
    do_gemm(xn_buf, iw_sg, g_buf, false, nullptr, true);
    do_gemm(xn_buf, iw_su, u_buf, false, nullptr, false);
    silu_mul_k<<<ew_blocks, blk256, 0, stream>>>(g_buf, u_buf, g_buf, (int)ND);
    do_gemm(g_buf, iw_sd, ys_buf, false, nullptr, true);
    moe_combine_k<<<ew_blocks, blk256, 0, stream>>>(x_buf, ybuf[0], ybuf[1], ys_buf, eidx);

    h_update_k<<<ew_blocks, blk256, 0, stream>>>(h_buf, e_buf, x_buf, lti_logA, lti_logdt,
                                                 lti_B, gate_emb, t);
  }

  // ---- coda block ----
  attn_block(iw_coda_wq, iw_coda_wk, iw_coda_wv, iw_coda_wo, coda_an, coda_qn, coda_kn, h_buf);
  swiglu_block(iw_coda_g, iw_coda_u, iw_coda_d, coda_fn, h_buf);

  // ---- lm head ----
  rms_k<<<kN, blk256, 0, stream>>>(h_buf, final_norm, xn_buf);
  do_gemm(xn_buf, iw_lm, out, false, nullptr, true);
}

// Round 2
// 7941.344 us; speedup vs baseline: 5.1373x; 1.9513x over previous
//
#include <hip/hip_runtime.h>
#include <math.h>

// ---------------------------------------------------------------------------
// KashfModel forward on MI355X. Round 2: GEMM fusion (qkv / g|u / moe-up6 /
// batched down3), rms+split and silu+split fusion, flash-attn 2-wave k-split,
// single batched weight-conversion launch. GEMM core unchanged from round 1.
// Legacy fp32 fallback retained if workspace too small (~430 MB needed).
// ---------------------------------------------------------------------------

namespace {

constexpr int kB = 2, kT = 1024, kV = 50257, kD = 1024, kE = 512;
constexpr int kH = 16, kHD = 64, kEXP = 1024, kDFF = 1365, kL = 6;
constexpr int kN = kB * kT; // 2048 tokens
constexpr float kCAP = 50.0f;
constexpr float kEPS = 1e-6f;

typedef __attribute__((ext_vector_type(8))) short bf16x8;
typedef __attribute__((ext_vector_type(4))) float f32x4;

// ---- bf16 helpers (RNE) ----------------------------------------------------
__device__ inline unsigned short f2bf(float f) {
  unsigned int x = __float_as_uint(f);
  unsigned int r = x + 0x7fffu + ((x >> 16) & 1u);
  return (unsigned short)(r >> 16);
}
__device__ inline float bf2f(unsigned short u) {
  return __uint_as_float(((unsigned int)u) << 16);
}

// ---------------- rope tables: cos/sin[t][i], i<32, theta=500000 ------------
__global__ __launch_bounds__(256) void rope_tables_k(float* __restrict__ cost,
                                                     float* __restrict__ sint) {
  int idx = blockIdx.x * 256 + threadIdx.x; // kT*32 = 32768
  int t = idx >> 5, i = idx & 31;
  float inv = __powf(500000.0f, -(float)i / 32.0f);
  float ang = (float)t * inv;
  cost[idx] = cosf(ang);
  sint[idx] = sinf(ang);
}

// ---------------- batched weight transpose+split ----------------------------
// Each sub-weight W[K][M] f32 (row-major) -> plane[Moff+m][Kp] bf16 hi/lo.
struct WTab {
  const float* W[32];
  unsigned short* h[32];
  unsigned short* l[32];
  int K[32], M[32], Kp[32], Moff[32], tile0[32], mt[32];
  int count;
};

__global__ __launch_bounds__(256) void wconv_all_k(WTab tab) {
  int bid = blockIdx.x;
  int w = 0;
  while (w + 1 < tab.count && bid >= tab.tile0[w + 1]) w++;
  const int lt = bid - tab.tile0[w];
  const int mt = tab.mt[w];
  const int mtile = lt % mt, ktile = lt / mt;
  const int K = tab.K[w], M = tab.M[w], Kp = tab.Kp[w], Moff = tab.Moff[w];
  const float* W = tab.W[w];
  unsigned short* Wh = tab.h[w];
  unsigned short* Wl = tab.l[w];
  const int kb = ktile * 32, mb = mtile * 32;
  __shared__ float tile[32][33];
#pragma unroll
  for (int i = 0; i < 4; i++) {
    int kk = (threadIdx.x >> 5) + i * 8;
    int mm = threadIdx.x & 31;
    int gk = kb + kk, gm = mb + mm;
    tile[kk][mm] = (gk < K && gm < M) ? W[(size_t)gk * M + gm] : 0.0f;
  }
  __syncthreads();
#pragma unroll
  for (int i = 0; i < 4; i++) {
    int mm = (threadIdx.x >> 5) + i * 8;
    int kk = threadIdx.x & 31;
    int gm = mb + mm, gk = kb + kk;
    if (gm < M) {
      float v = tile[kk][mm];
      unsigned short hh = f2bf(v);
      size_t idx = (size_t)(Moff + gm) * Kp + gk;
      Wh[idx] = hh;
      Wl[idx] = f2bf(v - bf2f(hh));
    }
  }
}

// ---------------- activation split (embed gather) ---------------------------
__global__ __launch_bounds__(256) void aconv_k(const float* __restrict__ X,
                                               unsigned short* __restrict__ Ah,
                                               unsigned short* __restrict__ Al,
                                               int K, int Kp,
                                               const int* __restrict__ tok) {
  int n = blockIdx.x;
  size_t src = tok ? (size_t)tok[n] : (size_t)n;
  const float* row = X + src * K;
  unsigned short* ah = Ah + (size_t)n * Kp;
  unsigned short* al = Al + (size_t)n * Kp;
  for (int k = threadIdx.x; k < Kp; k += 256) {
    float v = (k < K) ? row[k] : 0.0f;
    unsigned short h = f2bf(v);
    ah[k] = h;
    al[k] = f2bf(v - bf2f(h));
  }
}

// ---------------- fused RMS norm + split (optional fp32 out) ----------------
template <bool XOUT>
__global__ __launch_bounds__(256) void rms_aconv_k(const float* __restrict__ x,
                                                   const float* __restrict__ w,
                                                   unsigned short* __restrict__ Ah,
                                                   unsigned short* __restrict__ Al,
                                                   float* __restrict__ xn) {
  int n = blockIdx.x;
  const float* row = x + (size_t)n * kD;
  float v[4];
  float ss = 0.0f;
#pragma unroll
  for (int i = 0; i < 4; i++) {
    v[i] = row[threadIdx.x + i * 256];
    ss += v[i] * v[i];
  }
#pragma unroll
  for (int off = 32; off > 0; off >>= 1) ss += __shfl_down(ss, off);
  __shared__ float red[4];
  if ((threadIdx.x & 63) == 0) red[threadIdx.x >> 6] = ss;
  __syncthreads();
  float tot = red[0] + red[1] + red[2] + red[3];
  float scale = rsqrtf(tot * (1.0f / kD) + kEPS);
  unsigned short* ah = Ah + (size_t)n * kD;
  unsigned short* al = Al + (size_t)n * kD;
  float* orow = XOUT ? xn + (size_t)n * kD : nullptr;
#pragma unroll
  for (int i = 0; i < 4; i++) {
    int d = threadIdx.x + i * 256;
    float val = v[i] * scale * w[d];
    unsigned short h = f2bf(val);
    ah[d] = h;
    al[d] = f2bf(val - bf2f(h));
    if (XOUT) orow[d] = val;
  }
}

// ---------------- fused silu(g)*u + split -----------------------------------
// C[n][ldc]; z = blockIdx.y. g col = gbase+z*gstride+k ; u col = g col + udelta.
__global__ __launch_bounds__(256) void aconv_silu_k(const float* __restrict__ C,
                                                    int ldc, int gbase, int gstride,
                                                    int udelta, int KK, int Kp,
                                                    unsigned short* __restrict__ Ah,
                                                    unsigned short* __restrict__ Al) {
  int n = blockIdx.x, z = blockIdx.y;
  const float* row = C + (size_t)n * ldc;
  int go = gbase + z * gstride;
  unsigned short* ah = Ah + ((size_t)z * kN + n) * Kp;
  unsigned short* al = Al + ((size_t)z * kN + n) * Kp;
  for (int k = threadIdx.x; k < Kp; k += 256) {
    float res = 0.0f;
    if (k < KK) {
      float g = row[go + k];
      float u = row[go + udelta + k];
      res = g / (1.0f + __expf(-g)) * u;
    }
    unsigned short h = f2bf(res);
    ah[k] = h;
    al[k] = f2bf(res - bf2f(h));
  }
}

// ---------------- MFMA GEMM, hi/lo split, z-batched -------------------------
// C[2048 x M] = (Ah+Al)[2048 x Kp] @ (Bh+Bl)^T ; B planes are [M][Kp].
// 128x128 tile, BK=32, 4 waves each 64x64 (4x4 frags of 16x16x32 bf16).
// acc += ah*bh + ah*bl + al*bh  (al*bl dropped: ~2^-18 relative)
template <bool ACCUM>
__global__ __launch_bounds__(256, 2) void gemm_bf16s_k(
    const unsigned short* __restrict__ Ah, const unsigned short* __restrict__ Al,
    const unsigned short* __restrict__ Bh, const unsigned short* __restrict__ Bl,
    float* __restrict__ C, int Kp, int M, long sA, long sB, long sC) {
  const int z = blockIdx.z;
  Ah += (size_t)z * sA;
  Al += (size_t)z * sA;
  Bh += (size_t)z * sB;
  Bl += (size_t)z * sB;
  C += (size_t)z * sC;
  __shared__ unsigned short As[2][128][40]; // [plane][row][k], pad 40 (80B rows)
  __shared__ unsigned short Bs[2][128][40]; // [plane][col][k]
  const int tid = threadIdx.x;
  const int wave = tid >> 6, lane = tid & 63;
  const int l15 = lane & 15, l4 = lane >> 4;
  const int wr = (wave >> 1) * 64, wc = (wave & 1) * 64;
  const int rowBase = blockIdx.y * 128, colBase = blockIdx.x * 128;

  f32x4 acc[4][4];
#pragma unroll
  for (int m = 0; m < 4; m++)
#pragma unroll
    for (int n = 0; n < 4; n++)
#pragma unroll
      for (int r = 0; r < 4; r++) acc[m][n][r] = 0.0f;

  for (int k0 = 0; k0 < Kp; k0 += 32) {
#pragma unroll
    for (int i = 0; i < 4; i++) {
      int flin = tid + (i & 1) * 256; // 0..511
      int r = flin >> 2;              // 0..127
      int kc = (flin & 3) * 8;        // short offset within 32
      int pl = i >> 1;
      const unsigned short* sa =
          (pl ? Al : Ah) + (size_t)(rowBase + r) * Kp + k0 + kc;
      *(int4*)&As[pl][r][kc] = *(const int4*)sa;
      int4 bv = {0, 0, 0, 0};
      int col = colBase + r;
      if (col < M)
        bv = *(const int4*)((pl ? Bl : Bh) + (size_t)col * Kp + k0 + kc);
      *(int4*)&Bs[pl][r][kc] = bv;
    }
    __syncthreads();

    bf16x8 ah[4], al[4], bh[4], bl[4];
#pragma unroll
    for (int m = 0; m < 4; m++) {
      ah[m] = *reinterpret_cast<const bf16x8*>(&As[0][wr + m * 16 + l15][l4 * 8]);
      al[m] = *reinterpret_cast<const bf16x8*>(&As[1][wr + m * 16 + l15][l4 * 8]);
    }
#pragma unroll
    for (int n = 0; n < 4; n++) {
      bh[n] = *reinterpret_cast<const bf16x8*>(&Bs[0][wc + n * 16 + l15][l4 * 8]);
      bl[n] = *reinterpret_cast<const bf16x8*>(&Bs[1][wc + n * 16 + l15][l4 * 8]);
    }
#pragma unroll
    for (int m = 0; m < 4; m++)
#pragma unroll
      for (int n = 0; n < 4; n++) {
        acc[m][n] = __builtin_amdgcn_mfma_f32_16x16x32_bf16(ah[m], bh[n], acc[m][n], 0, 0, 0);
        acc[m][n] = __builtin_amdgcn_mfma_f32_16x16x32_bf16(ah[m], bl[n], acc[m][n], 0, 0, 0);
        acc[m][n] = __builtin_amdgcn_mfma_f32_16x16x32_bf16(al[m], bh[n], acc[m][n], 0, 0, 0);
      }
    __syncthreads();
  }

  // epilogue: D layout col=lane&15, row=(lane>>4)*4+reg
  const int row0 = rowBase + wr + l4 * 4;
#pragma unroll
  for (int m = 0; m < 4; m++) {
#pragma unroll
    for (int n = 0; n < 4; n++) {
      int col = colBase + wc + n * 16 + l15;
      if (col < M) {
#pragma unroll
        for (int r = 0; r < 4; r++) {
          size_t idx = (size_t)(row0 + m * 16 + r) * M + col;
          if (ACCUM)
            C[idx] += acc[m][n][r];
          else
            C[idx] = acc[m][n][r];
        }
      }
    }
  }
}

// ---------------- per-head RMS (over 64) + RoPE, in place, strided ----------
__global__ __launch_bounds__(256) void qk_norm_rope_k(float* __restrict__ base,
                                                      const float* __restrict__ nw,
                                                      const float* __restrict__ cost,
                                                      const float* __restrict__ sint,
                                                      int nh, int tokStride) {
  int row = blockIdx.x * 16 + (threadIdx.x >> 4);
  int lane = threadIdx.x & 15;
  int n = row / nh, sub = row % nh;
  float* r = base + (size_t)n * tokStride + sub * 64;
  float v[4];
  float ss = 0.0f;
#pragma unroll
  for (int i = 0; i < 4; i++) {
    v[i] = r[lane * 4 + i];
    ss += v[i] * v[i];
  }
#pragma unroll
  for (int m = 1; m < 16; m <<= 1) ss += __shfl_xor(ss, m);
  float scale = rsqrtf(ss * (1.0f / 64.0f) + kEPS);
  float nv[4];
#pragma unroll
  for (int i = 0; i < 4; i++) nv[i] = v[i] * scale * nw[lane * 4 + i];
  int tpos = n & (kT - 1);
  float c0 = cost[tpos * 32 + lane * 2 + 0], s0 = sint[tpos * 32 + lane * 2 + 0];
  float c1 = cost[tpos * 32 + lane * 2 + 1], s1 = sint[tpos * 32 + lane * 2 + 1];
  r[lane * 4 + 0] = nv[0] * c0 - nv[1] * s0;
  r[lane * 4 + 1] = nv[0] * s0 + nv[1] * c0;
  r[lane * 4 + 2] = nv[2] * c1 - nv[3] * s1;
  r[lane * 4 + 3] = nv[2] * s1 + nv[3] * c1;
}

// ---------------- flash attention v2: 2 waves split k-tiles -----------------
// qkv layout [N][1152]: q at h*64, k at 1024, v at 1088. Output split bf16
// into Oh/Ol [N][1024] (wo GEMM A operand).
__global__ __launch_bounds__(128) void attn_flash2_k(const float* __restrict__ qkv,
                                                     unsigned short* __restrict__ Oh,
                                                     unsigned short* __restrict__ Ol) {
  const int b = blockIdx.z, h = blockIdx.y, qb = blockIdx.x;
  const int w = threadIdx.x >> 6, lane = threadIdx.x & 63;
  const int t = qb * 64 + lane;
  const float* qrow = qkv + (size_t)(b * kT + t) * 1152 + h * 64;
  float qreg[64];
  {
    const float4* q4 = reinterpret_cast<const float4*>(qrow);
#pragma unroll
    for (int i = 0; i < 16; i++) {
      float4 qq = q4[i];
      qreg[4 * i + 0] = qq.x * 0.125f;
      qreg[4 * i + 1] = qq.y * 0.125f;
      qreg[4 * i + 2] = qq.z * 0.125f;
      qreg[4 * i + 3] = qq.w * 0.125f;
    }
  }
  float O[64];
#pragma unroll
  for (int d = 0; d < 64; d++) O[d] = 0.0f;
  float m = -INFINITY, l = 0.0f;

  __shared__ float ks[2][32][64];
  __shared__ float vs[2][32][64];
  __shared__ float mS[64], lS[64];
  __shared__ float OS[64][65];

  const int smax = qb * 64 + 63;
  for (int s0 = w * 32; s0 <= smax; s0 += 64) {
#pragma unroll 4
    for (int r = 0; r < 32; r++) {
      const float* kr = qkv + (size_t)(b * kT + s0 + r) * 1152 + 1024;
      ks[w][r][lane] = kr[lane];
      vs[w][r][lane] = kr[64 + lane];
    }
    asm volatile("s_waitcnt lgkmcnt(0)" ::: "memory");
    int jend = t - s0 + 1;
    if (jend > 32) jend = 32;
    for (int j = 0; j < jend; j++) {
      float dot = 0.0f;
#pragma unroll
      for (int d = 0; d < 64; d++) dot += qreg[d] * ks[w][j][d];
      float sc = kCAP * tanhf(dot * (1.0f / kCAP));
      float mn = fmaxf(m, sc);
      float corr = __expf(m - mn);
      float p = __expf(sc - mn);
      l = l * corr + p;
#pragma unroll
      for (int d = 0; d < 64; d++) O[d] = O[d] * corr + p * vs[w][j][d];
      m = mn;
    }
  }
  if (w == 1) {
    mS[lane] = m;
    lS[lane] = l;
#pragma unroll
    for (int d = 0; d < 64; d++) OS[lane][d] = O[d];
  }
  __syncthreads();
  if (w == 0) {
    float m1 = mS[lane], l1 = lS[lane];
    float mn = fmaxf(m, m1); // wave 0 always has >=1 tile -> m finite
    float c0 = __expf(m - mn);
    float c1 = __expf(m1 - mn); // m1=-inf -> 0
    float L = l * c0 + l1 * c1;
    float invl = 1.0f / L;
    size_t obase = (size_t)(b * kT + t) * 1024 + h * 64;
#pragma unroll
    for (int d = 0; d < 64; d++) {
      float val = (O[d] * c0 + OS[lane][d] * c1) * invl;
      unsigned short hh = f2bf(val);
      Oh[obase + d] = hh;
      Ol[obase + d] = f2bf(val - bf2f(hh));
    }
  }
}

// ---------------- router: wave per token, fp32 dot, argmax ------------------
__global__ __launch_bounds__(256) void router_k(const float* __restrict__ xn,
                                                const float* __restrict__ rw,
                                                const float* __restrict__ rb,
                                                int* __restrict__ eidx) {
  int n = blockIdx.x * 4 + (threadIdx.x >> 6);
  int lane = threadIdx.x & 63;
  const float* row = xn + (size_t)n * kD;
  float l0 = 0.0f, l1 = 0.0f;
  for (int kk = lane; kk < kD; kk += 64) {
    float xv = row[kk];
    l0 += xv * rw[kk * 2 + 0];
    l1 += xv * rw[kk * 2 + 1];
  }
#pragma unroll
  for (int off = 32; off > 0; off >>= 1) {
    l0 += __shfl_down(l0, off);
    l1 += __shfl_down(l1, off);
  }
  if (lane == 0) eidx[n] = (l1 + rb[1] > l0 + rb[0]) ? 1 : 0;
}

// ---------------- loop-position embedding add -------------------------------
__global__ __launch_bounds__(256) void add_loop_emb_k(const float* __restrict__ h,
                                                      float* __restrict__ x, int t) {
  int idx = blockIdx.x * 256 + threadIdx.x;
  int d = idx & (kD - 1);
  float add = 0.0f;
  if (d < 256) {
    float f = __powf(10000.0f, -(float)d / 256.0f);
    add = sinf((float)t * f);
  } else if (d < 512) {
    float f = __powf(10000.0f, -(float)(d - 256) / 256.0f);
    add = cosf((float)t * f);
  }
  x[idx] = h[idx] + add;
}

// ---------------- fused MoE combine + LTI h update --------------------------
// y3: [3][N][D] = {expert0, expert1, shared}
__global__ __launch_bounds__(256) void combine_update_k(
    float* __restrict__ h, const float* __restrict__ e, const float* __restrict__ x,
    const float* __restrict__ y3, const int* __restrict__ eidx,
    const float* __restrict__ logA, const float* __restrict__ logdt,
    const float* __restrict__ Bv, const float* __restrict__ gate, int t) {
  int idx = blockIdx.x * 256 + threadIdx.x;
  int n = idx >> 10, d = idx & (kD - 1);
  const size_t ND = (size_t)kN * kD;
  const float* ye = y3 + (eidx[n] ? ND : 0);
  const float* ys = y3 + 2 * ND;
  float xv = x[idx] + ye[idx] + ys[idx];
  float z = logdt[0] + logA[d];
  z = fminf(fmaxf(z, -20.0f), 20.0f);
  float A = __expf(-__expf(z));
  float gv = gate[t];
  float g = 1.0f / (1.0f + __expf(-gv));
  h[idx] = A * h[idx] + Bv[d] * e[idx] + g * xv;
}

// ======================= legacy fp32 fallback kernels =======================
template <bool ACCUM, bool EMBED>
__global__ __launch_bounds__(256) void gemm128_k(const float* __restrict__ A,
                                                 const float* __restrict__ Bm,
                                                 float* __restrict__ C, int K, int M,
                                                 const int* __restrict__ tok) {
  __shared__ float As[8][132];
  __shared__ float Bs[8][132];
  const int tid = threadIdx.x;
  const int tx = tid & 15, ty = tid >> 4;
  const int rowBase = blockIdx.y * 128;
  const int colBase = blockIdx.x * 128;
  float acc[8][8];
#pragma unroll
  for (int i = 0; i < 8; i++)
#pragma unroll
    for (int j = 0; j < 8; j++) acc[i][j] = 0.0f;
  for (int k0 = 0; k0 < K; k0 += 8) {
#pragma unroll
    for (int i = 0; i < 4; i++) {
      int lin = tid + i * 256;
      int r = lin >> 3, kk = lin & 7;
      int gk = k0 + kk;
      float v = 0.0f;
      if (gk < K) {
        int row = rowBase + r;
        size_t arow = EMBED ? (size_t)tok[row] : (size_t)row;
        v = A[arow * K + gk];
      }
      As[kk][r] = v;
    }
#pragma unroll
    for (int i = 0; i < 4; i++) {
      int lin = tid + i * 256;
      int kk = lin >> 7, c = lin & 127;
      int gk = k0 + kk, gc = colBase + c;
      Bs[kk][c] = (gk < K && gc < M) ? Bm[(size_t)gk * M + gc] : 0.0f;
    }
    __syncthreads();
#pragma unroll
    for (int kk = 0; kk < 8; kk++) {
      float av[8], bv[8];
#pragma unroll
      for (int i = 0; i < 8; i++) av[i] = As[kk][ty * 8 + i];
#pragma unroll
      for (int j = 0; j < 8; j++) bv[j] = Bs[kk][tx * 8 + j];
#pragma unroll
      for (int i = 0; i < 8; i++)
#pragma unroll
        for (int j = 0; j < 8; j++) acc[i][j] += av[i] * bv[j];
    }
    __syncthreads();
  }
#pragma unroll
  for (int i = 0; i < 8; i++) {
    int r = rowBase + ty * 8 + i;
#pragma unroll
    for (int j = 0; j < 8; j++) {
      int c = colBase + tx * 8 + j;
      if (c < M) {
        size_t idx = (size_t)r * M + c;
        if (ACCUM)
          C[idx] += acc[i][j];
        else
          C[idx] = acc[i][j];
      }
    }
  }
}

__global__ __launch_bounds__(256) void rms_k(const float* __restrict__ x,
                                             const float* __restrict__ w,
                                             float* __restrict__ out) {
  int n = blockIdx.x;
  const float* row = x + (size_t)n * kD;
  float v[4];
  float ss = 0.0f;
#pragma unroll
  for (int i = 0; i < 4; i++) {
    v[i] = row[threadIdx.x + i * 256];
    ss += v[i] * v[i];
  }
#pragma unroll
  for (int off = 32; off > 0; off >>= 1) ss += __shfl_down(ss, off);
  __shared__ float red[4];
  if ((threadIdx.x & 63) == 0) red[threadIdx.x >> 6] = ss;
  __syncthreads();
  float tot = red[0] + red[1] + red[2] + red[3];
  float scale = rsqrtf(tot * (1.0f / kD) + kEPS);
  float* orow = out + (size_t)n * kD;
#pragma unroll
  for (int i = 0; i < 4; i++) {
    int d = threadIdx.x + i * 256;
    orow[d] = v[i] * scale * w[d];
  }
}

__global__ __launch_bounds__(64) void attn_flash_legacy_k(const float* __restrict__ q,
                                                          const float* __restrict__ k,
                                                          const float* __restrict__ v,
                                                          float* __restrict__ out) {
  const int b = blockIdx.z, h = blockIdx.y, qb = blockIdx.x;
  const int tid = threadIdx.x;
  const int t = qb * 64 + tid;
  const float* qrow = q + (((size_t)(b * kT + t)) * kH + h) * kHD;
  float qreg[64];
#pragma unroll
  for (int d = 0; d < 64; d++) qreg[d] = qrow[d] * 0.125f;
  float O[64];
#pragma unroll
  for (int d = 0; d < 64; d++) O[d] = 0.0f;
  float m = -INFINITY, l = 0.0f;
  __shared__ float ks[32][64];
  __shared__ float vs[32][64];
  const int smax = qb * 64 + 63;
  for (int s0 = 0; s0 <= smax; s0 += 32) {
#pragma unroll 4
    for (int r = 0; r < 32; r++) {
      ks[r][tid] = k[((size_t)(b * kT + s0 + r)) * 64 + tid];
      vs[r][tid] = v[((size_t)(b * kT + s0 + r)) * 64 + tid];
    }
    __syncthreads();
    int jend = t - s0 + 1;
    if (jend > 32) jend = 32;
    for (int j = 0; j < jend; j++) {
      float dot = 0.0f;
#pragma unroll
      for (int d = 0; d < 64; d++) dot += qreg[d] * ks[j][d];
      float sc = kCAP * tanhf(dot * (1.0f / kCAP));
      float mn = fmaxf(m, sc);
      float corr = __expf(m - mn);
      float p = __expf(sc - mn);
      l = l * corr + p;
#pragma unroll
      for (int d = 0; d < 64; d++) O[d] = O[d] * corr + p * vs[j][d];
      m = mn;
    }
    __syncthreads();
  }
  float invl = 1.0f / l;
  float* orow = out + ((size_t)(b * kT + t)) * (kH * kHD) + h * kHD;
#pragma unroll
  for (int d = 0; d < 64; d++) orow[d] = O[d] * invl;
}

__global__ __launch_bounds__(256) void silu_mul_k(const float* __restrict__ g,
                                                  const float* __restrict__ u,
                                                  float* __restrict__ out, int n) {
  int i = blockIdx.x * 256 + threadIdx.x;
  if (i < n) {
    float gv = g[i];
    float s = gv / (1.0f + __expf(-gv));
    out[i] = s * u[i];
  }
}

__global__ __launch_bounds__(256) void moe_combine_k(float* __restrict__ x,
                                                     const float* __restrict__ y0,
                                                     const float* __restrict__ y1,
                                                     const float* __restrict__ ys,
                                                     const int* __restrict__ eidx) {
  int idx = blockIdx.x * 256 + threadIdx.x;
  int n = idx >> 10;
  const float* y = eidx[n] ? y1 : y0;
  x[idx] += y[idx] + ys[idx];
}

__global__ __launch_bounds__(256) void h_update_k(float* __restrict__ h,
                                                  const float* __restrict__ e,
                                                  const float* __restrict__ x,
                                                  const float* __restrict__ logA,
                                                  const float* __restrict__ logdt,
                                                  const float* __restrict__ Bv,
                                                  const float* __restrict__ gate, int t) {
  int idx = blockIdx.x * 256 + threadIdx.x;
  int d = idx & (kD - 1);
  float z = logdt[0] + logA[d];
  z = fminf(fmaxf(z, -20.0f), 20.0f);
  float A = __expf(-__expf(z));
  float gv = gate[t];
  float g = 1.0f / (1.0f + __expf(-gv));
  h[idx] = A * h[idx] + Bv[d] * e[idx] + g * x[idx];
}

} // namespace

// ---------------------------------------------------------------------------
extern "C" void kernel_launch(void* const* d_in, const int* in_sizes, int n_in,
                              void* d_out, int out_size, void* d_ws, size_t ws_size,
                              hipStream_t stream) {
  const int* tok = (const int*)d_in[0];
  const float* embed_table = (const float*)d_in[1];
  const float* embed_proj = (const float*)d_in[2];
  const float* pre_an = (const float*)d_in[3];
  const float* pre_fn = (const float*)d_in[4];
  const float* pre_wq = (const float*)d_in[5];
  const float* pre_wk = (const float*)d_in[6];
  const float* pre_wv = (const float*)d_in[7];
  const float* pre_wo = (const float*)d_in[8];
  const float* pre_qn = (const float*)d_in[9];
  const float* pre_kn = (const float*)d_in[10];
  const float* pre_g = (const float*)d_in[11];
  const float* pre_u = (const float*)d_in[12];
  const float* pre_d = (const float*)d_in[13];
  const float* rec_an = (const float*)d_in[14];
  const float* rec_fn = (const float*)d_in[15];
  const float* rec_wq = (const float*)d_in[16];
  const float* rec_wk = (const float*)d_in[17];
  const float* rec_wv = (const float*)d_in[18];
  const float* rec_wo = (const float*)d_in[19];
  const float* rec_qn = (const float*)d_in[20];
  const float* rec_kn = (const float*)d_in[21];
  const float* rec_router = (const float*)d_in[22];
  const float* rec_rbias = (const float*)d_in[23];
  const float* rec_eg = (const float*)d_in[24];
  const float* rec_eu = (const float*)d_in[25];
  const float* rec_ed = (const float*)d_in[26];
  const float* rec_sg = (const float*)d_in[27];
  const float* rec_su = (const float*)d_in[28];
  const float* rec_sd = (const float*)d_in[29];
  const float* lti_logA = (const float*)d_in[30];
  const float* lti_logdt = (const float*)d_in[31];
  const float* lti_B = (const float*)d_in[32];
  const float* gate_emb = (const float*)d_in[33];
  const float* coda_an = (const float*)d_in[34];
  const float* coda_fn = (const float*)d_in[35];
  const float* coda_wq = (const float*)d_in[36];
  const float* coda_wk = (const float*)d_in[37];
  const float* coda_wv = (const float*)d_in[38];
  const float* coda_wo = (const float*)d_in[39];
  const float* coda_qn = (const float*)d_in[40];
  const float* coda_kn = (const float*)d_in[41];
  const float* coda_g = (const float*)d_in[42];
  const float* coda_u = (const float*)d_in[43];
  const float* coda_d = (const float*)d_in[44];
  const float* final_norm = (const float*)d_in[45];
  const float* lm_head = (const float*)d_in[46];
  float* out = (float*)d_out;

  // ---- workspace bump allocator ----
  char* base = (char*)d_ws;
  size_t off = 0;
  auto alloc = [&](size_t bytes) -> void* {
    void* p = base + off;
    off += (bytes + 255) & ~(size_t)255;
    return p;
  };

  const size_t ND = (size_t)kN * kD;      // 2097152
  const size_t NDFF = (size_t)kN * kDFF;  // 2795520
  // shared fp32 buffers
  float* e_buf = (float*)alloc(ND * 4);
  float* h_buf = (float*)alloc(ND * 4);
  float* x_buf = (float*)alloc(ND * 4);
  float* xn_buf = (float*)alloc(ND * 4);
  float* cost = (float*)alloc((size_t)kT * 32 * 4);
  float* sint = (float*)alloc((size_t)kT * 32 * 4);
  int* eidx = (int*)alloc((size_t)kN * 4);
  const int maxKp = 1376;
  unsigned short* Ah = (unsigned short*)alloc((size_t)kN * maxKp * 2);
  unsigned short* Al = (unsigned short*)alloc((size_t)kN * maxKp * 2);

  // union region: legacy {q,a,ys,g,u,k,v} OR new {big_c, Ah3, Al3}
  const size_t legacy_bytes = (3 * ND + 2 * NDFF + 2 * (size_t)kN * 64) * 4;
  const size_t big_c_bytes = (size_t)kN * 6144 * 4;
  const size_t a3_bytes = (size_t)3 * kN * 1024 * 2;
  const size_t new_bytes = big_c_bytes + 2 * a3_bytes;
  char* Ubase = (char*)alloc(legacy_bytes > new_bytes ? legacy_bytes : new_bytes);
  // new-path carve
  float* big_c = (float*)Ubase;
  unsigned short* Ah3 = (unsigned short*)(Ubase + big_c_bytes);
  unsigned short* Al3 = (unsigned short*)(Ubase + big_c_bytes + a3_bytes);
  float* y3 = big_c; // down-proj output aliases big_c (up6 output consumed by then)
  // legacy carve
  float* L_q = (float*)Ubase;
  float* L_a = L_q + ND;
  float* L_ys = L_a + ND;
  float* L_g = L_ys + ND;
  float* L_u = L_g + NDFF;
  float* L_k = L_u + NDFF;
  float* L_v = L_k + (size_t)kN * 64;

  // ---- weight planes + conversion table ----
  struct Plane {
    unsigned short *h, *l;
    int Kp;
  };
  auto mkplane = [&](int Kp, int M) -> Plane {
    Plane p;
    p.h = (unsigned short*)alloc((size_t)M * Kp * 2);
    p.l = (unsigned short*)alloc((size_t)M * Kp * 2);
    p.Kp = Kp;
    return p;
  };
  WTab tab;
  int ne = 0, tt = 0;
  auto went = [&](const float* W, const Plane& p, int K, int M, int Moff) {
    tab.W[ne] = W;
    tab.h[ne] = p.h;
    tab.l[ne] = p.l;
    tab.K[ne] = K;
    tab.M[ne] = M;
    tab.Kp[ne] = p.Kp;
    tab.Moff[ne] = Moff;
    tab.tile0[ne] = tt;
    tab.mt[ne] = (M + 31) / 32;
    tt += tab.mt[ne] * (p.Kp / 32);
    ne++;
  };

  Plane P_embed = mkplane(512, 1024);
  went(embed_proj, P_embed, kE, kD, 0);
  Plane P_pre_qkv = mkplane(1024, 1152);
  went(pre_wq, P_pre_qkv, kD, 1024, 0);
  went(pre_wk, P_pre_qkv, kD, 64, 1024);
  went(pre_wv, P_pre_qkv, kD, 64, 1088);
  Plane P_pre_wo = mkplane(1024, 1024);
  went(pre_wo, P_pre_wo, kH * kHD, kD, 0);
  Plane P_pre_gu = mkplane(1024, 2 * kDFF);
  went(pre_g, P_pre_gu, kD, kDFF, 0);
  went(pre_u, P_pre_gu, kD, kDFF, kDFF);
  Plane P_pre_d = mkplane(1376, 1024);
  went(pre_d, P_pre_d, kDFF, kD, 0);
  Plane P_rec_qkv = mkplane(1024, 1152);
  went(rec_wq, P_rec_qkv, kD, 1024, 0);
  went(rec_wk, P_rec_qkv, kD, 64, 1024);
  went(rec_wv, P_rec_qkv, kD, 64, 1088);
  Plane P_rec_wo = mkplane(1024, 1024);
  went(rec_wo, P_rec_wo, kH * kHD, kD, 0);
  Plane P_up6 = mkplane(1024, 6144);
  went(rec_eg, P_up6, kD, kEXP, 0);
  went(rec_eu, P_up6, kD, kEXP, 1024);
  went(rec_eg + (size_t)kD * kEXP, P_up6, kD, kEXP, 2048);
  went(rec_eu + (size_t)kD * kEXP, P_up6, kD, kEXP, 3072);
  went(rec_sg, P_up6, kD, kEXP, 4096);
  went(rec_su, P_up6, kD, kEXP, 5120);
  Plane P_dn3 = mkplane(1024, 3072);
  went(rec_ed, P_dn3, kEXP, kD, 0);
  went(rec_ed + (size_t)kEXP * kD, P_dn3, kEXP, kD, 1024);
  went(rec_sd, P_dn3, kEXP, kD, 2048);
  Plane P_coda_qkv = mkplane(1024, 1152);
  went(coda_wq, P_coda_qkv, kD, 1024, 0);
  went(coda_wk, P_coda_qkv, kD, 64, 1024);
  went(coda_wv, P_coda_qkv, kD, 64, 1088);
  Plane P_coda_wo = mkplane(1024, 1024);
  went(coda_wo, P_coda_wo, kH * kHD, kD, 0);
  Plane P_coda_gu = mkplane(1024, 2 * kDFF);
  went(coda_g, P_coda_gu, kD, kDFF, 0);
  went(coda_u, P_coda_gu, kD, kDFF, kDFF);
  Plane P_coda_d = mkplane(1376, 1024);
  went(coda_d, P_coda_d, kDFF, kD, 0);
  Plane P_lm = mkplane(1024, kV);
  went(lm_head, P_lm, kD, kV, 0);
  tab.count = ne;

  const bool use_mfma = (off <= ws_size);
  const dim3 blk256(256);
  const int ew_blocks = (int)(ND / 256);

  rope_tables_k<<<kT * 32 / 256, blk256, 0, stream>>>(cost, sint);

  if (use_mfma) {
    // ---------------- new fused MFMA path ----------------
    wconv_all_k<<<tt, blk256, 0, stream>>>(tab);

    auto gemm = [&](const unsigned short* ah, const unsigned short* al,
                    const Plane& p, float* C, int M, bool accum, int nz,
                    long sA, long sB, long sC) {
      dim3 g((M + 127) / 128, kN / 128, nz);
      if (accum)
        gemm_bf16s_k<true><<<g, blk256, 0, stream>>>(ah, al, p.h, p.l, C, p.Kp, M, sA, sB, sC);
      else
        gemm_bf16s_k<false><<<g, blk256, 0, stream>>>(ah, al, p.h, p.l, C, p.Kp, M, sA, sB, sC);
    };

    // embedding: gather+split then GEMM
    aconv_k<<<kN, blk256, 0, stream>>>(embed_table, Ah, Al, kE, 512, tok);
    gemm(Ah, Al, P_embed, e_buf, kD, false, 1, 0, 0, 0);
    hipMemcpyAsync(h_buf, e_buf, ND * sizeof(float), hipMemcpyDeviceToDevice, stream);

    auto attn_block = [&](const Plane& pqkv, const Plane& pwo, const float* an,
                          const float* qn, const float* kn, float* target) {
      rms_aconv_k<false><<<kN, blk256, 0, stream>>>(target, an, Ah, Al, nullptr);
      gemm(Ah, Al, pqkv, big_c, 1152, false, 1, 0, 0, 0);
      qk_norm_rope_k<<<kN * kH / 16, blk256, 0, stream>>>(big_c, qn, cost, sint, kH, 1152);
      qk_norm_rope_k<<<kN / 16, blk256, 0, stream>>>(big_c + 1024, kn, cost, sint, 1, 1152);
      attn_flash2_k<<<dim3(kT / 64, kH, kB), dim3(128), 0, stream>>>(big_c, Ah, Al);
      gemm(Ah, Al, pwo, target, kD, true, 1, 0, 0, 0);
    };

    auto swiglu_block = [&](const Plane& pgu, const Plane& pd, const float* fn,
                            float* target) {
      rms_aconv_k<false><<<kN, blk256, 0, stream>>>(target, fn, Ah, Al, nullptr);
      gemm(Ah, Al, pgu, big_c, 2 * kDFF, false, 1, 0, 0, 0);
      aconv_silu_k<<<dim3(kN, 1), blk256, 0, stream>>>(big_c, 2 * kDFF, 0, 0, kDFF,
                                                       kDFF, 1376, Ah, Al);
      gemm(Ah, Al, pd, target, kD, true, 1, 0, 0, 0);
    };

    attn_block(P_pre_qkv, P_pre_wo, pre_an, pre_qn, pre_kn, h_buf);
    swiglu_block(P_pre_gu, P_pre_d, pre_fn, h_buf);

    for (int t = 0; t < kL; t++) {
      add_loop_emb_k<<<ew_blocks, blk256, 0, stream>>>(h_buf, x_buf, t);
      attn_block(P_rec_qkv, P_rec_wo, rec_an, rec_qn, rec_kn, x_buf);

      // MoE
      rms_aconv_k<true><<<kN, blk256, 0, stream>>>(x_buf, rec_fn, Ah, Al, xn_buf);
      router_k<<<kN / 4, blk256, 0, stream>>>(xn_buf, rec_router, rec_rbias, eidx);
      gemm(Ah, Al, P_up6, big_c, 6144, false, 1, 0, 0, 0);
      aconv_silu_k<<<dim3(kN, 3), blk256, 0, stream>>>(big_c, 6144, 0, 2048, 1024,
                                                       1024, 1024, Ah3, Al3);
      gemm(Ah3, Al3, P_dn3, y3, kD, false, 3, (long)kN * 1024,
           (long)1024 * 1024, (long)kN * 1024);
      combine_update_k<<<ew_blocks, blk256, 0, stream>>>(h_buf, e_buf, x_buf, y3, eidx,
                                                         lti_logA, lti_logdt, lti_B,
                                                         gate_emb, t);
    }

    attn_block(P_coda_qkv, P_coda_wo, coda_an, coda_qn, coda_kn, h_buf);
    swiglu_block(P_coda_gu, P_coda_d, coda_fn, h_buf);

    rms_aconv_k<false><<<kN, blk256, 0, stream>>>(h_buf, final_norm, Ah, Al, nullptr);
    gemm(Ah, Al, P_lm, out, kV, false, 1, 0, 0, 0);
    return;
  }

  // ---------------- legacy fp32 fallback ----------------
  const dim3 g_D(kD / 128, kN / 128);
  const dim3 g_64(1, kN / 128);
  const dim3 g_DFF((kDFF + 127) / 128, kN / 128);
  const dim3 g_V((kV + 127) / 128, kN / 128);

  gemm128_k<false, true><<<g_D, blk256, 0, stream>>>(embed_table, embed_proj, e_buf, kE, kD, tok);
  hipMemcpyAsync(h_buf, e_buf, ND * sizeof(float), hipMemcpyDeviceToDevice, stream);

  auto attn_blockL = [&](const float* an, const float* wq, const float* wk,
                         const float* wv, const float* wo, const float* qn,
                         const float* kn, float* target) {
    rms_k<<<kN, blk256, 0, stream>>>(target, an, xn_buf);
    gemm128_k<false, false><<<g_D, blk256, 0, stream>>>(xn_buf, wq, L_q, kD, kH * kHD, nullptr);
    gemm128_k<false, false><<<g_64, blk256, 0, stream>>>(xn_buf, wk, L_k, kD, kHD, nullptr);
    gemm128_k<false, false><<<g_64, blk256, 0, stream>>>(xn_buf, wv, L_v, kD, kHD, nullptr);
    qk_norm_rope_k<<<kN * kH / 16, blk256, 0, stream>>>(L_q, qn, cost, sint, kH, 1024);
    qk_norm_rope_k<<<kN / 16, blk256, 0, stream>>>(L_k, kn, cost, sint, 1, 64);
    attn_flash_legacy_k<<<dim3(kT / 64, kH, kB), dim3(64), 0, stream>>>(L_q, L_k, L_v, L_a);
    gemm128_k<true, false><<<g_D, blk256, 0, stream>>>(L_a, wo, target, kH * kHD, kD, nullptr);
  };

  auto swiglu_blockL = [&](const float* fn, const float* wg, const float* wu,
                           const float* wd, float* target) {
    rms_k<<<kN, blk256, 0, stream>>>(target, fn, xn_buf);
    gemm128_k<false, false><<<g_DFF, blk256, 0, stream>>>(xn_buf, wg, L_g, kD, kDFF, nullptr);
    gemm128_k<false, false><<<g_DFF, blk256, 0, stream>>>(xn_buf, wu, L_u, kD, kDFF, nullptr);
    silu_mul_k<<<(int)((NDFF + 255) / 256), blk256, 0, stream>>>(L_g, L_u, L_g, (int)NDFF);
    gemm128_k<true, false><<<g_D, blk256, 0, stream>>>(L_g, wd, target, kDFF, kD, nullptr);
  };

  attn_blockL(pre_an, pre_wq, pre_wk, pre_wv, pre_wo, pre_qn, pre_kn, h_buf);
  swiglu_blockL(pre_fn, pre_g, pre_u, pre_d, h_buf);

  for (int t = 0; t < kL; t++) {
    add_loop_emb_k<<<ew_blocks, blk256, 0, stream>>>(h_buf, x_buf, t);
    attn_blockL(rec_an, rec_wq, rec_wk, rec_wv, rec_wo, rec_qn, rec_kn, x_buf);
    rms_k<<<kN, blk256, 0, stream>>>(x_buf, rec_fn, xn_buf);
    router_k<<<kN / 4, blk256, 0, stream>>>(xn_buf, rec_router, rec_rbias, eidx);
    float* ybuf[2] = {L_q, L_a};
    for (int ex = 0; ex < 2; ex++) {
      const float* eg = rec_eg + (size_t)ex * kD * kEXP;
      const float* eu = rec_eu + (size_t)ex * kD * kEXP;
      const float* ed = rec_ed + (size_t)ex * kEXP * kD;
      gemm128_k<false, false><<<g_D, blk256, 0, stream>>>(xn_buf, eg, L_g, kD, kEXP, nullptr);
      gemm128_k<false, false><<<g_D, blk256, 0, stream>>>(xn_buf, eu, L_u, kD, kEXP, nullptr);
      silu_mul_k<<<ew_blocks, blk256, 0, stream>>>(L_g, L_u, L_g, (int)ND);
      gemm128_k<false, false><<<g_D, blk256, 0, stream>>>(L_g, ed, ybuf[ex], kEXP, kD, nullptr);
    }
    gemm128_k<false, false><<<g_D, blk256, 0, stream>>>(xn_buf, rec_sg, L_g, kD, kEXP, nullptr);
    gemm128_k<false, false><<<g_D, blk256, 0, stream>>>(xn_buf, rec_su, L_u, kD, kEXP, nullptr);
    silu_mul_k<<<ew_blocks, blk256, 0, stream>>>(L_g, L_u, L_g, (int)ND);
    gemm128_k<false, false><<<g_D, blk256, 0, stream>>>(L_g, rec_sd, L_ys, kEXP, kD, nullptr);
    moe_combine_k<<<ew_blocks, blk256, 0, stream>>>(x_buf, ybuf[0], ybuf[1], L_ys, eidx);
    h_update_k<<<ew_blocks, blk256, 0, stream>>>(h_buf, e_buf, x_buf, lti_logA, lti_logdt,
                                                 lti_B, gate_emb, t);
  }

  attn_blockL(coda_an, coda_wq, coda_wk, coda_wv, coda_wo, coda_qn, coda_kn, h_buf);
  swiglu_blockL(coda_fn, coda_g, coda_u, coda_d, h_buf);

  rms_k<<<kN, blk256, 0, stream>>>(h_buf, final_norm, xn_buf);
  gemm128_k<false, false><<<g_V, blk256, 0, stream>>>(xn_buf, lm_head, out, kD, kV, nullptr);
}